// Round 13
// baseline (118.528 us; speedup 1.0000x reference)
//
#include <hip/hip_runtime.h>
#include <hip/hip_bf16.h>

// DendriticLayerSiLU: out = silu(softmax-gated template proj) * (x @ W^T)
// N=4096 tokens, K=2048, H=1024, 32 windows of 64.
// Round 13: r10 base (16x16x32 MFMA, BK=64 window==K-step, 160 KB dbuf,
// chunk^(row&7) swizzle [0 conflicts], one barrier/K-step, raw v_exp_f32
// gate, setprio) + EPILOG software-pipelined one step back (winA/winB
// static double-state): the exp/fma VALU work of window t overlaps the
// ds_read+MFMA phase of window t+1. First EPILOG runs on zeros -> den+1,
// corrected by den-1 at the end (validated r8). 32x32@BK=64 abandoned:
// r11/r12 proved an irreducible +4cy/read bank penalty (bank = 4*slot
// only when rows are 128 B; swizzle-invariant).

typedef __attribute__((ext_vector_type(8))) short short8;
typedef __attribute__((ext_vector_type(4))) float f32x4;

#define N_TOK 4096
#define K_DIM 2048
#define H_DIM 1024
#define BM 128
#define BH 128
#define BK 64
#define LDSZ (BM * BK)            // 8192 shorts = 16 KB per array

#define X_ELEMS (N_TOK * K_DIM)   // 8388608
#define W_ELEMS (H_DIM * K_DIM)   // 2097152
#define WS_NEED ((size_t)(2 * X_ELEMS + 3 * W_ELEMS) * 2)  // 46,137,344 B

#define XB (X_ELEMS / 8 / 256)    // 4096 prepass blocks for X
#define WB (W_ELEMS / 8 / 256)    // 1024 for W, 1024 for T

#define LOG2E 1.4426950408889634f
#define LN2   0.6931471805599453f

// raw v_exp_f32 (computes 2^x, ~1 ULP) — 1 instruction, fabs folds free.
#if defined(__has_builtin)
#if __has_builtin(__builtin_amdgcn_exp2f)
#define EXP2RAW(x) __builtin_amdgcn_exp2f(x)
#endif
#endif
#ifndef EXP2RAW
__device__ __forceinline__ float exp2raw_asm(float x) {
    float r;
    asm("v_exp_f32 %0, %1" : "=v"(r) : "v"(x));
    return r;
}
#define EXP2RAW(x) exp2raw_asm(x)
#endif

__device__ __forceinline__ unsigned short f2bf(float f) {
    unsigned int u = __float_as_uint(f);
    u += 0x7FFFu + ((u >> 16) & 1u);    // round-to-nearest-even
    return (unsigned short)(u >> 16);
}
__device__ __forceinline__ float bf2f(unsigned short h) {
    return __uint_as_float(((unsigned int)h) << 16);
}

__device__ __forceinline__ void cvt_split(f32x4 a, f32x4 b, short8& vh, short8& vl) {
#pragma unroll
    for (int i = 0; i < 4; ++i) {
        float f = a[i];
        unsigned short h = f2bf(f);
        vh[i] = (short)h;
        vl[i] = (short)f2bf(f - bf2f(h));
    }
#pragma unroll
    for (int i = 0; i < 4; ++i) {
        float f = b[i];
        unsigned short h = f2bf(f);
        vh[i + 4] = (short)h;
        vl[i + 4] = (short)f2bf(f - bf2f(h));
    }
}
__device__ __forceinline__ short8 cvt_hi(f32x4 a, f32x4 b) {
    short8 v;
#pragma unroll
    for (int i = 0; i < 4; ++i) { v[i] = (short)f2bf(a[i]); v[i + 4] = (short)f2bf(b[i]); }
    return v;
}

#define MFMA16(A, B, C) __builtin_amdgcn_mfma_f32_16x16x32_bf16(A, B, C, 0, 0, 0)

// ---------------------------------------------------------------- prepass ---
// X,W -> hi/lo bf16 split; T -> bf16 scaled by log2e (exp2-based softmax).
__global__ __launch_bounds__(256) void prepass_all(
    const float* __restrict__ X, const float* __restrict__ W,
    const float* __restrict__ T,
    unsigned short* __restrict__ XH, unsigned short* __restrict__ XL,
    unsigned short* __restrict__ WH, unsigned short* __restrict__ WL,
    unsigned short* __restrict__ TH)
{
    int b = blockIdx.x;
    if (b < XB + WB) {
        const float* src; unsigned short *hi, *lo; int i;
        if (b < XB) { src = X; hi = XH; lo = XL; i = b * 256 + threadIdx.x; }
        else        { src = W; hi = WH; lo = WL; i = (b - XB) * 256 + threadIdx.x; }
        const float* p = src + (size_t)i * 8;
        f32x4 a = *(const f32x4*)p;
        f32x4 c = *(const f32x4*)(p + 4);
        short8 vh, vl;
        cvt_split(a, c, vh, vl);
        *(short8*)&hi[(size_t)i * 8] = vh;
        *(short8*)&lo[(size_t)i * 8] = vl;
    } else {
        int i = (b - XB - WB) * 256 + threadIdx.x;
        const float* p = T + (size_t)i * 8;
        f32x4 a = *(const f32x4*)p;
        f32x4 c = *(const f32x4*)(p + 4);
#pragma unroll
        for (int j = 0; j < 4; ++j) { a[j] *= LOG2E; c[j] *= LOG2E; }
        *(short8*)&TH[(size_t)i * 8] = cvt_hi(a, c);
    }
}

// ------------------------------------------------------------- main GEMM ----
#define GLL(gp, lp) __builtin_amdgcn_global_load_lds(                      \
        (const __attribute__((address_space(1))) void*)(gp),               \
        (__attribute__((address_space(3))) void*)(lp), 16, 0, 0)

__global__ __launch_bounds__(512) void dend_gemm(
    const unsigned short* __restrict__ XH, const unsigned short* __restrict__ XL,
    const unsigned short* __restrict__ WH, const unsigned short* __restrict__ WL,
    const unsigned short* __restrict__ TH, float* __restrict__ O)
{
    // arrays: 0=x_hi 1=x_lo 2=w_hi 3=w_lo 4=t_hi ; [128][64] shorts each;
    // double-buffered -> 160 KB (full CU LDS, 1 block/CU by design).
    __shared__ __align__(16) short lds[2][5][LDSZ];

    const int tid  = threadIdx.x;
    const int lane = tid & 63;
    const int wv   = tid >> 6;    // 0..7
    const int wm   = wv >> 2;     // 0..1  (64 token-rows each)
    const int wn   = wv & 3;      // 0..3  (32 units each)

    const int bid     = blockIdx.x;
    const int logical = (bid & 7) * 32 + (bid >> 3);   // XCD-chunked swizzle
    const int hb   = logical >> 5;   // 0..7
    const int nb   = logical & 31;   // 0..31
    const int row0 = nb * BM;
    const int col0 = hb * BH;

    // ---- staging (frozen r9/r10, measured 0 conflicts): row = 64 shorts =
    // 8 chunks of 16B; content(row, slot) = logical chunk slot ^ (row & 7).
    // GLL (1 KB linear): lane l -> row +(l>>3), slot l&7 =>
    //   source chunk = (l&7) ^ (l>>3).  Two GLLs per 16-row wave stripe.
    const int srow8 = lane >> 3;                 // 0..7
    const int schk  = (lane & 7) ^ srow8;        // pre-swizzled source chunk
    const size_t xbase = (size_t)(row0 + wv * 16 + srow8) * K_DIM + schk * 8;
    const size_t wbase = (size_t)(col0 + wv * 16 + srow8) * K_DIM + schk * 8;
    const size_t rstep8 = (size_t)8 * K_DIM;     // +8 rows
    const int dst0 = (wv * 16) * BK;             // short index of stripe row 0
    const int dst1 = dst0 + 8 * BK;

#define STAGE(buf, t) do {                                                 \
        const size_t ko = (size_t)(t) * BK;                                \
        GLL(XH + xbase + ko,          &lds[buf][0][dst0]);                 \
        GLL(XH + xbase + rstep8 + ko, &lds[buf][0][dst1]);                 \
        GLL(XL + xbase + ko,          &lds[buf][1][dst0]);                 \
        GLL(XL + xbase + rstep8 + ko, &lds[buf][1][dst1]);                 \
        GLL(WH + wbase + ko,          &lds[buf][2][dst0]);                 \
        GLL(WH + wbase + rstep8 + ko, &lds[buf][2][dst1]);                 \
        GLL(WL + wbase + ko,          &lds[buf][3][dst0]);                 \
        GLL(WL + wbase + rstep8 + ko, &lds[buf][3][dst1]);                 \
        GLL(TH + wbase + ko,          &lds[buf][4][dst0]);                 \
        GLL(TH + wbase + rstep8 + ko, &lds[buf][4][dst1]);                 \
    } while (0)

    // ---- fragment read offsets (frozen r10, measured 0 conflicts).
    const int g = lane >> 4;
    int a_off[4][2], b_off[2][2];
#pragma unroll
    for (int mi = 0; mi < 4; ++mi) {
        int r = wm * 64 + mi * 16 + (lane & 15);
#pragma unroll
        for (int kc = 0; kc < 2; ++kc)
            a_off[mi][kc] = r * BK + ((kc * 4 + g) ^ (r & 7)) * 8;
    }
#pragma unroll
    for (int nj = 0; nj < 2; ++nj) {
        int r = wn * 32 + nj * 16 + (lane & 15);
#pragma unroll
        for (int kc = 0; kc < 2; ++kc)
            b_off[nj][kc] = r * BK + ((kc * 4 + g) ^ (r & 7)) * 8;
    }

    const f32x4 zeroc = (f32x4)0.0f;
    f32x4 lin[4][2], num[4][2], den[4][2], winA[4][2], winB[4][2];
#pragma unroll
    for (int mi = 0; mi < 4; ++mi)
#pragma unroll
        for (int nj = 0; nj < 2; ++nj) {
            lin[mi][nj] = zeroc; num[mi][nj] = zeroc; den[mi][nj] = zeroc;
            winB[mi][nj] = zeroc;   // first EPILOG sees zeros -> den += 1
        }

    // MFMA phase for one K-step (window) into WIN (setprio-wrapped).
#define COMPUTE(buf, WIN) do {                                             \
        _Pragma("unroll")                                                  \
        for (int kc = 0; kc < 2; ++kc) {                                   \
            short8 bwh[2], bwl[2], bth[2];                                 \
            _Pragma("unroll")                                              \
            for (int nj = 0; nj < 2; ++nj) {                               \
                bwh[nj] = *(const short8*)&lds[buf][2][b_off[nj][kc]];     \
                bwl[nj] = *(const short8*)&lds[buf][3][b_off[nj][kc]];     \
                bth[nj] = *(const short8*)&lds[buf][4][b_off[nj][kc]];     \
            }                                                              \
            __builtin_amdgcn_s_setprio(1);                                 \
            _Pragma("unroll")                                              \
            for (int mi = 0; mi < 4; ++mi) {                               \
                short8 ah = *(const short8*)&lds[buf][0][a_off[mi][kc]];   \
                short8 al = *(const short8*)&lds[buf][1][a_off[mi][kc]];   \
                _Pragma("unroll")                                          \
                for (int nj = 0; nj < 2; ++nj) {                           \
                    lin[mi][nj] = MFMA16(ah, bwh[nj], lin[mi][nj]);        \
                    lin[mi][nj] = MFMA16(al, bwh[nj], lin[mi][nj]);        \
                    lin[mi][nj] = MFMA16(ah, bwl[nj], lin[mi][nj]);        \
                    WIN[mi][nj] = MFMA16(ah, bth[nj],                      \
                                         (kc == 0) ? zeroc : WIN[mi][nj]); \
                }                                                          \
            }                                                              \
            __builtin_amdgcn_s_setprio(0);                                 \
        }                                                                  \
    } while (0)

    // EPILOG on the PREVIOUS step's window (no dep on current reads/MFMAs
    // -> scheduler interleaves it into MFMA stalls). e = v_exp_f32(|d|) =
    // exp(|a|) since T carries log2e from the prepass.
#define EPILOG(PW) do {                                                    \
        _Pragma("unroll")                                                  \
        for (int mi = 0; mi < 4; ++mi)                                     \
        _Pragma("unroll")                                                  \
        for (int nj = 0; nj < 2; ++nj)                                     \
        _Pragma("unroll")                                                  \
        for (int i = 0; i < 4; ++i) {                                      \
            float d = PW[mi][nj][i];                                       \
            float e = EXP2RAW(fabsf(d));                                   \
            den[mi][nj][i] += e;                                           \
            num[mi][nj][i] = fmaf(e, d, num[mi][nj][i]);                   \
        }                                                                  \
    } while (0)

    STAGE(0, 0);
    __syncthreads();

    // One barrier per K=64 step (frozen r9/r10 structure). EPILOG of the
    // previous window rides inside the current window's compute region.
#pragma unroll 1
    for (int w = 0; w < 16; ++w) {
        const int t0 = 2 * w;
        STAGE(1, t0 + 1);
        COMPUTE(0, winA);
        EPILOG(winB);
        __syncthreads();
        if (t0 + 2 < 32) STAGE(0, t0 + 2);
        COMPUTE(1, winB);
        EPILOG(winA);
        __syncthreads();
    }
    EPILOG(winB);   // window 31

    // Final epilogue: den has +1 from the initial zero-window EPILOG.
    // g = (num/(den-1))*ln2, silu, multiply, store.
#pragma unroll
    for (int mi = 0; mi < 4; ++mi)
#pragma unroll
        for (int nj = 0; nj < 2; ++nj)
#pragma unroll
            for (int i = 0; i < 4; ++i) {
                float dd   = den[mi][nj][i] - 1.0f;
                float gg   = (num[mi][nj][i] / dd) * LN2;
                float gate = gg / (1.0f + __expf(-gg));
                float val  = gate * lin[mi][nj][i];
                int r = row0 + wm * 64 + mi * 16 + (lane >> 4) * 4 + i;
                int c = col0 + wn * 32 + nj * 16 + (lane & 15);
                O[(size_t)r * H_DIM + c] = val;
            }
#undef STAGE
#undef COMPUTE
#undef EPILOG
}

// ------------------------------------------------- fallback (round-1 path) --
__global__ __launch_bounds__(512) void dend_fused_v0(
    const float* __restrict__ X, const float* __restrict__ T,
    const float* __restrict__ W, float* __restrict__ O)
{
    __shared__ __align__(16) short lds[2][5][128 * 32];

    const int tid  = threadIdx.x;
    const int lane = tid & 63;
    const int wv   = tid >> 6;
    const int wm   = wv >> 2;
    const int wn   = wv & 3;

    const int bid     = blockIdx.x;
    const int logical = (bid & 7) * 32 + (bid >> 3);
    const int hb   = logical >> 5;
    const int nb   = logical & 31;
    const int row0 = nb * 128;
    const int col0 = hb * 128;

    const int srow  = tid >> 2;
    const int schn  = tid & 3;
    const int sslot = schn ^ ((srow >> 1) & 3);
    const int swoff = srow * 32 + sslot * 8;

    const float* gx = X + (size_t)(row0 + srow) * K_DIM + schn * 8;
    const float* gw = W + (size_t)(col0 + srow) * K_DIM + schn * 8;
    const float* gt = T + (size_t)(col0 + srow) * K_DIM + schn * 8;

    const int g = lane >> 4;
    int a_off[4], b_off[2];
#pragma unroll
    for (int mi = 0; mi < 4; ++mi) {
        int r = wm * 64 + mi * 16 + (lane & 15);
        a_off[mi] = r * 32 + (g ^ ((r >> 1) & 3)) * 8;
    }
#pragma unroll
    for (int nj = 0; nj < 2; ++nj) {
        int r = wn * 32 + nj * 16 + (lane & 15);
        b_off[nj] = r * 32 + (g ^ ((r >> 1) & 3)) * 8;
    }

    const f32x4 zeroc = (f32x4)0.0f;
    f32x4 lin[4][2], num[4][2], den[4][2], win[4][2];
#pragma unroll
    for (int mi = 0; mi < 4; ++mi)
#pragma unroll
        for (int nj = 0; nj < 2; ++nj) {
            lin[mi][nj] = zeroc; num[mi][nj] = zeroc; den[mi][nj] = zeroc;
        }

    f32x4 rx0, rx1, rw0, rw1, rt0, rt1;

#define LOADS(t) do {                                                   \
        const float* px = gx + (size_t)(t) * 32;                        \
        const float* pw = gw + (size_t)(t) * 32;                        \
        const float* pt = gt + (size_t)(t) * 32;                        \
        rx0 = *(const f32x4*)(px); rx1 = *(const f32x4*)(px + 4);       \
        rw0 = *(const f32x4*)(pw); rw1 = *(const f32x4*)(pw + 4);       \
        rt0 = *(const f32x4*)(pt); rt1 = *(const f32x4*)(pt + 4);       \
    } while (0)

#define WRITE(buf) do {                                                 \
        short8 vh, vl;                                                  \
        cvt_split(rx0, rx1, vh, vl);                                    \
        *(short8*)&lds[buf][0][swoff] = vh;                             \
        *(short8*)&lds[buf][1][swoff] = vl;                             \
        cvt_split(rw0, rw1, vh, vl);                                    \
        *(short8*)&lds[buf][2][swoff] = vh;                             \
        *(short8*)&lds[buf][3][swoff] = vl;                             \
        *(short8*)&lds[buf][4][swoff] = cvt_hi(rt0, rt1);               \
    } while (0)

#define COMPUTE(buf, ZW) do {                                           \
        short8 bwh[2], bwl[2], bth[2];                                  \
        _Pragma("unroll")                                               \
        for (int nj = 0; nj < 2; ++nj) {                                \
            bwh[nj] = *(const short8*)&lds[buf][2][b_off[nj]];          \
            bwl[nj] = *(const short8*)&lds[buf][3][b_off[nj]];          \
            bth[nj] = *(const short8*)&lds[buf][4][b_off[nj]];          \
        }                                                               \
        _Pragma("unroll")                                               \
        for (int mi = 0; mi < 4; ++mi) {                                \
            short8 ah = *(const short8*)&lds[buf][0][a_off[mi]];        \
            short8 al = *(const short8*)&lds[buf][1][a_off[mi]];        \
            _Pragma("unroll")                                           \
            for (int nj = 0; nj < 2; ++nj) {                            \
                lin[mi][nj] = MFMA16(ah, bwh[nj], lin[mi][nj]);         \
                lin[mi][nj] = MFMA16(al, bwh[nj], lin[mi][nj]);         \
                lin[mi][nj] = MFMA16(ah, bwl[nj], lin[mi][nj]);         \
                win[mi][nj] = MFMA16(ah, bth[nj], (ZW) ? zeroc : win[mi][nj]); \
            }                                                           \
        }                                                               \
    } while (0)

#define EPILOG() do {                                                   \
        _Pragma("unroll")                                               \
        for (int mi = 0; mi < 4; ++mi)                                  \
        _Pragma("unroll")                                               \
        for (int nj = 0; nj < 2; ++nj)                                  \
        _Pragma("unroll")                                               \
        for (int i = 0; i < 4; ++i) {                                   \
            float d = win[mi][nj][i];                                   \
            float e = __expf(fabsf(d));                                 \
            den[mi][nj][i] += e;                                        \
            num[mi][nj][i] = fmaf(e, d, num[mi][nj][i]);                \
        }                                                               \
    } while (0)

    LOADS(0);
    WRITE(0);
    __syncthreads();

#pragma unroll 1
    for (int w = 0; w < 32; ++w) {
        const int t0 = 2 * w;
        LOADS(t0 + 1);
        COMPUTE(0, true);
        __syncthreads();
        WRITE(1);
        __syncthreads();
        const bool more = (w < 31);
        if (more) LOADS(t0 + 2);
        COMPUTE(1, false);
        EPILOG();
        __syncthreads();
        if (more) WRITE(0);
        __syncthreads();
    }

#pragma unroll
    for (int mi = 0; mi < 4; ++mi)
#pragma unroll
        for (int nj = 0; nj < 2; ++nj)
#pragma unroll
            for (int i = 0; i < 4; ++i) {
                float gg   = num[mi][nj][i] / den[mi][nj][i];
                float gate = gg / (1.0f + __expf(-gg));
                float val  = gate * lin[mi][nj][i];
                int r = row0 + wm * 64 + mi * 16 + (lane >> 4) * 4 + i;
                int c = col0 + wn * 32 + nj * 16 + (lane & 15);
                O[(size_t)r * H_DIM + c] = val;
            }
#undef LOADS
#undef WRITE
#undef COMPUTE
#undef EPILOG
}

extern "C" void kernel_launch(void* const* d_in, const int* in_sizes, int n_in,
                              void* d_out, int out_size, void* d_ws, size_t ws_size,
                              hipStream_t stream) {
    const float* X = (const float*)d_in[0];   // x [4096,2048]
    const float* T = (const float*)d_in[1];   // template_flat [1024,2048]
    const float* W = (const float*)d_in[2];   // weights [1024,2048]
    float* O = (float*)d_out;                 // [4096,1024]
    (void)in_sizes; (void)n_in; (void)out_size;

    if (ws_size >= WS_NEED) {
        unsigned short* XHp = (unsigned short*)d_ws;
        unsigned short* XLp = XHp + X_ELEMS;
        unsigned short* WHp = XLp + X_ELEMS;
        unsigned short* WLp = WHp + W_ELEMS;
        unsigned short* THp = WLp + W_ELEMS;
        prepass_all<<<XB + 2 * WB, 256, 0, stream>>>(X, W, T, XHp, XLp, WHp, WLp, THp);
        dend_gemm<<<256, 512, 0, stream>>>(XHp, XLp, WHp, WLp, THp, O);
    } else {
        dend_fused_v0<<<256, 512, 0, stream>>>(X, T, W, O);
    }
}

// Round 14
// 101.965 us; speedup vs baseline: 1.1624x; 1.1624x over previous
//
#include <hip/hip_runtime.h>
#include <hip/hip_bf16.h>

// DendriticLayerSiLU: out = silu(softmax-gated template proj) * (x @ W^T)
// N=4096 tokens, K=2048, H=1024, 32 windows of 64.
// Round 14: r10 base (16x16x32 MFMA, BK=64 window==K-step, chunk^(row&7)
// swizzle [0 conflicts], one barrier/K-step, raw v_exp_f32 gate, setprio,
// inline EPILOG) with T moved out of LDS: per-wave T B-fragments are loaded
// global->VGPR, double-state prefetched one step ahead (tbA/tbB; the
// per-step __syncthreads vmcnt(0) drain guarantees arrival — no r7 hazard).
// LDS 160->128 KB, ds_reads 28->24/wave-step, staging 10->8 GLL.
// __launch_bounds__(512,2) raises the VGPR cap to 256 (1 block/CU is
// LDS-forced anyway), removing r10's ~2 MB spill and funding the T regs.

typedef __attribute__((ext_vector_type(8))) short short8;
typedef __attribute__((ext_vector_type(4))) float f32x4;

#define N_TOK 4096
#define K_DIM 2048
#define H_DIM 1024
#define BM 128
#define BH 128
#define BK 64
#define LDSZ (BM * BK)            // 8192 shorts = 16 KB per array

#define X_ELEMS (N_TOK * K_DIM)   // 8388608
#define W_ELEMS (H_DIM * K_DIM)   // 2097152
#define WS_NEED ((size_t)(2 * X_ELEMS + 3 * W_ELEMS) * 2)  // 46,137,344 B

#define XB (X_ELEMS / 8 / 256)    // 4096 prepass blocks for X
#define WB (W_ELEMS / 8 / 256)    // 1024 for W, 1024 for T

#define LOG2E 1.4426950408889634f
#define LN2   0.6931471805599453f

// raw v_exp_f32 (computes 2^x, ~1 ULP) — 1 instruction, fabs folds free.
#if defined(__has_builtin)
#if __has_builtin(__builtin_amdgcn_exp2f)
#define EXP2RAW(x) __builtin_amdgcn_exp2f(x)
#endif
#endif
#ifndef EXP2RAW
__device__ __forceinline__ float exp2raw_asm(float x) {
    float r;
    asm("v_exp_f32 %0, %1" : "=v"(r) : "v"(x));
    return r;
}
#define EXP2RAW(x) exp2raw_asm(x)
#endif

__device__ __forceinline__ unsigned short f2bf(float f) {
    unsigned int u = __float_as_uint(f);
    u += 0x7FFFu + ((u >> 16) & 1u);    // round-to-nearest-even
    return (unsigned short)(u >> 16);
}
__device__ __forceinline__ float bf2f(unsigned short h) {
    return __uint_as_float(((unsigned int)h) << 16);
}

__device__ __forceinline__ void cvt_split(f32x4 a, f32x4 b, short8& vh, short8& vl) {
#pragma unroll
    for (int i = 0; i < 4; ++i) {
        float f = a[i];
        unsigned short h = f2bf(f);
        vh[i] = (short)h;
        vl[i] = (short)f2bf(f - bf2f(h));
    }
#pragma unroll
    for (int i = 0; i < 4; ++i) {
        float f = b[i];
        unsigned short h = f2bf(f);
        vh[i + 4] = (short)h;
        vl[i + 4] = (short)f2bf(f - bf2f(h));
    }
}
__device__ __forceinline__ short8 cvt_hi(f32x4 a, f32x4 b) {
    short8 v;
#pragma unroll
    for (int i = 0; i < 4; ++i) { v[i] = (short)f2bf(a[i]); v[i + 4] = (short)f2bf(b[i]); }
    return v;
}

#define MFMA16(A, B, C) __builtin_amdgcn_mfma_f32_16x16x32_bf16(A, B, C, 0, 0, 0)

// ---------------------------------------------------------------- prepass ---
// X,W -> hi/lo bf16 split; T -> bf16 scaled by log2e (exp2-based softmax).
__global__ __launch_bounds__(256) void prepass_all(
    const float* __restrict__ X, const float* __restrict__ W,
    const float* __restrict__ T,
    unsigned short* __restrict__ XH, unsigned short* __restrict__ XL,
    unsigned short* __restrict__ WH, unsigned short* __restrict__ WL,
    unsigned short* __restrict__ TH)
{
    int b = blockIdx.x;
    if (b < XB + WB) {
        const float* src; unsigned short *hi, *lo; int i;
        if (b < XB) { src = X; hi = XH; lo = XL; i = b * 256 + threadIdx.x; }
        else        { src = W; hi = WH; lo = WL; i = (b - XB) * 256 + threadIdx.x; }
        const float* p = src + (size_t)i * 8;
        f32x4 a = *(const f32x4*)p;
        f32x4 c = *(const f32x4*)(p + 4);
        short8 vh, vl;
        cvt_split(a, c, vh, vl);
        *(short8*)&hi[(size_t)i * 8] = vh;
        *(short8*)&lo[(size_t)i * 8] = vl;
    } else {
        int i = (b - XB - WB) * 256 + threadIdx.x;
        const float* p = T + (size_t)i * 8;
        f32x4 a = *(const f32x4*)p;
        f32x4 c = *(const f32x4*)(p + 4);
#pragma unroll
        for (int j = 0; j < 4; ++j) { a[j] *= LOG2E; c[j] *= LOG2E; }
        *(short8*)&TH[(size_t)i * 8] = cvt_hi(a, c);
    }
}

// ------------------------------------------------------------- main GEMM ----
#define GLL(gp, lp) __builtin_amdgcn_global_load_lds(                      \
        (const __attribute__((address_space(1))) void*)(gp),               \
        (__attribute__((address_space(3))) void*)(lp), 16, 0, 0)

__global__ __launch_bounds__(512, 2) void dend_gemm(
    const unsigned short* __restrict__ XH, const unsigned short* __restrict__ XL,
    const unsigned short* __restrict__ WH, const unsigned short* __restrict__ WL,
    const unsigned short* __restrict__ TH, float* __restrict__ O)
{
    // arrays: 0=x_hi 1=x_lo 2=w_hi 3=w_lo ; [128][64] shorts each;
    // double-buffered -> 128 KB (1 block/CU).
    __shared__ __align__(16) short lds[2][4][LDSZ];

    const int tid  = threadIdx.x;
    const int lane = tid & 63;
    const int wv   = tid >> 6;    // 0..7
    const int wm   = wv >> 2;     // 0..1  (64 token-rows each)
    const int wn   = wv & 3;      // 0..3  (32 units each)

    const int bid     = blockIdx.x;
    const int logical = (bid & 7) * 32 + (bid >> 3);   // XCD-chunked swizzle
    const int hb   = logical >> 5;   // 0..7
    const int nb   = logical & 31;   // 0..31
    const int row0 = nb * BM;
    const int col0 = hb * BH;

    // ---- staging (frozen r9/r10, measured 0 conflicts): row = 64 shorts =
    // 8 chunks of 16B; content(row, slot) = logical chunk slot ^ (row & 7).
    // GLL (1 KB linear): lane l -> row +(l>>3), slot l&7 =>
    //   source chunk = (l&7) ^ (l>>3).  Two GLLs per 16-row wave stripe.
    const int srow8 = lane >> 3;                 // 0..7
    const int schk  = (lane & 7) ^ srow8;        // pre-swizzled source chunk
    const size_t xbase = (size_t)(row0 + wv * 16 + srow8) * K_DIM + schk * 8;
    const size_t wbase = (size_t)(col0 + wv * 16 + srow8) * K_DIM + schk * 8;
    const size_t rstep8 = (size_t)8 * K_DIM;     // +8 rows
    const int dst0 = (wv * 16) * BK;             // short index of stripe row 0
    const int dst1 = dst0 + 8 * BK;

#define STAGE(buf, t) do {                                                 \
        const size_t ko = (size_t)(t) * BK;                                \
        GLL(XH + xbase + ko,          &lds[buf][0][dst0]);                 \
        GLL(XH + xbase + rstep8 + ko, &lds[buf][0][dst1]);                 \
        GLL(XL + xbase + ko,          &lds[buf][1][dst0]);                 \
        GLL(XL + xbase + rstep8 + ko, &lds[buf][1][dst1]);                 \
        GLL(WH + wbase + ko,          &lds[buf][2][dst0]);                 \
        GLL(WH + wbase + rstep8 + ko, &lds[buf][2][dst1]);                 \
        GLL(WL + wbase + ko,          &lds[buf][3][dst0]);                 \
        GLL(WL + wbase + rstep8 + ko, &lds[buf][3][dst1]);                 \
    } while (0)

    // ---- fragment read offsets (frozen r10, measured 0 conflicts).
    const int g = lane >> 4;
    int a_off[4][2], b_off[2][2];
#pragma unroll
    for (int mi = 0; mi < 4; ++mi) {
        int r = wm * 64 + mi * 16 + (lane & 15);
#pragma unroll
        for (int kc = 0; kc < 2; ++kc)
            a_off[mi][kc] = r * BK + ((kc * 4 + g) ^ (r & 7)) * 8;
    }
#pragma unroll
    for (int nj = 0; nj < 2; ++nj) {
        int r = wn * 32 + nj * 16 + (lane & 15);
#pragma unroll
        for (int kc = 0; kc < 2; ++kc)
            b_off[nj][kc] = r * BK + ((kc * 4 + g) ^ (r & 7)) * 8;
    }

    // ---- T B-fragments direct global->VGPR (bit-identical elements to the
    // old LDS path): row r = col0 + wn*32 + nj*16 + (lane&15), k = kc*32+g*8.
    const size_t tg0 = (size_t)(col0 + wn * 32 +      (lane & 15)) * K_DIM + g * 8;
    const size_t tg1 = (size_t)(col0 + wn * 32 + 16 + (lane & 15)) * K_DIM + g * 8;

#define TLOAD(TB, t) do {                                                  \
        const size_t ko = (size_t)(t) * BK;                                \
        TB[0][0] = *(const short8*)&TH[tg0 + ko];                          \
        TB[0][1] = *(const short8*)&TH[tg0 + ko + 32];                     \
        TB[1][0] = *(const short8*)&TH[tg1 + ko];                          \
        TB[1][1] = *(const short8*)&TH[tg1 + ko + 32];                     \
    } while (0)

    const f32x4 zeroc = (f32x4)0.0f;
    f32x4 lin[4][2], num[4][2], den[4][2], win[4][2];
#pragma unroll
    for (int mi = 0; mi < 4; ++mi)
#pragma unroll
        for (int nj = 0; nj < 2; ++nj) {
            lin[mi][nj] = zeroc; num[mi][nj] = zeroc; den[mi][nj] = zeroc;
        }

    // One K-step = one window: 2 K-halves of MFMA (setprio-wrapped), then
    // inline EPILOG on the completed win (frozen r10). T B-frags from TB.
#define COMP_EPI(buf, TB) do {                                             \
        _Pragma("unroll")                                                  \
        for (int kc = 0; kc < 2; ++kc) {                                   \
            short8 bwh[2], bwl[2];                                         \
            _Pragma("unroll")                                              \
            for (int nj = 0; nj < 2; ++nj) {                               \
                bwh[nj] = *(const short8*)&lds[buf][2][b_off[nj][kc]];     \
                bwl[nj] = *(const short8*)&lds[buf][3][b_off[nj][kc]];     \
            }                                                              \
            __builtin_amdgcn_s_setprio(1);                                 \
            _Pragma("unroll")                                              \
            for (int mi = 0; mi < 4; ++mi) {                               \
                short8 ah = *(const short8*)&lds[buf][0][a_off[mi][kc]];   \
                short8 al = *(const short8*)&lds[buf][1][a_off[mi][kc]];   \
                _Pragma("unroll")                                          \
                for (int nj = 0; nj < 2; ++nj) {                           \
                    lin[mi][nj] = MFMA16(ah, bwh[nj], lin[mi][nj]);        \
                    lin[mi][nj] = MFMA16(al, bwh[nj], lin[mi][nj]);        \
                    lin[mi][nj] = MFMA16(ah, bwl[nj], lin[mi][nj]);        \
                    win[mi][nj] = MFMA16(ah, TB[nj][kc],                   \
                                         (kc == 0) ? zeroc : win[mi][nj]); \
                }                                                          \
            }                                                              \
            __builtin_amdgcn_s_setprio(0);                                 \
        }                                                                  \
        _Pragma("unroll")                                                  \
        for (int mi = 0; mi < 4; ++mi)                                     \
        _Pragma("unroll")                                                  \
        for (int nj = 0; nj < 2; ++nj)                                     \
        _Pragma("unroll")                                                  \
        for (int i = 0; i < 4; ++i) {                                      \
            float d = win[mi][nj][i];                                      \
            float e = EXP2RAW(fabsf(d));                                   \
            den[mi][nj][i] += e;                                           \
            num[mi][nj][i] = fmaf(e, d, num[mi][nj][i]);                   \
        }                                                                  \
    } while (0)

    short8 tbA[2][2], tbB[2][2];

    TLOAD(tbA, 0);
    STAGE(0, 0);
    __syncthreads();

    // One barrier per K=64 step (frozen r9/r10 structure). T for step t+1 is
    // prefetched during step t; the barrier's vmcnt(0) drain certifies it.
#pragma unroll 1
    for (int w = 0; w < 16; ++w) {
        const int t0 = 2 * w;
        STAGE(1, t0 + 1);
        TLOAD(tbB, t0 + 1);
        COMP_EPI(0, tbA);
        __syncthreads();
        if (t0 + 2 < 32) {
            STAGE(0, t0 + 2);
            TLOAD(tbA, t0 + 2);
        }
        COMP_EPI(1, tbB);
        __syncthreads();
    }

    // Final epilogue: g = (num/den)*ln2, silu, multiply, store.
#pragma unroll
    for (int mi = 0; mi < 4; ++mi)
#pragma unroll
        for (int nj = 0; nj < 2; ++nj)
#pragma unroll
            for (int i = 0; i < 4; ++i) {
                float gg   = (num[mi][nj][i] / den[mi][nj][i]) * LN2;
                float gate = gg / (1.0f + __expf(-gg));
                float val  = gate * lin[mi][nj][i];
                int r = row0 + wm * 64 + mi * 16 + (lane >> 4) * 4 + i;
                int c = col0 + wn * 32 + nj * 16 + (lane & 15);
                O[(size_t)r * H_DIM + c] = val;
            }
#undef STAGE
#undef TLOAD
#undef COMP_EPI
}

// ------------------------------------------------- fallback (round-1 path) --
__global__ __launch_bounds__(512) void dend_fused_v0(
    const float* __restrict__ X, const float* __restrict__ T,
    const float* __restrict__ W, float* __restrict__ O)
{
    __shared__ __align__(16) short lds[2][5][128 * 32];

    const int tid  = threadIdx.x;
    const int lane = tid & 63;
    const int wv   = tid >> 6;
    const int wm   = wv >> 2;
    const int wn   = wv & 3;

    const int bid     = blockIdx.x;
    const int logical = (bid & 7) * 32 + (bid >> 3);
    const int hb   = logical >> 5;
    const int nb   = logical & 31;
    const int row0 = nb * 128;
    const int col0 = hb * 128;

    const int srow  = tid >> 2;
    const int schn  = tid & 3;
    const int sslot = schn ^ ((srow >> 1) & 3);
    const int swoff = srow * 32 + sslot * 8;

    const float* gx = X + (size_t)(row0 + srow) * K_DIM + schn * 8;
    const float* gw = W + (size_t)(col0 + srow) * K_DIM + schn * 8;
    const float* gt = T + (size_t)(col0 + srow) * K_DIM + schn * 8;

    const int g = lane >> 4;
    int a_off[4], b_off[2];
#pragma unroll
    for (int mi = 0; mi < 4; ++mi) {
        int r = wm * 64 + mi * 16 + (lane & 15);
        a_off[mi] = r * 32 + (g ^ ((r >> 1) & 3)) * 8;
    }
#pragma unroll
    for (int nj = 0; nj < 2; ++nj) {
        int r = wn * 32 + nj * 16 + (lane & 15);
        b_off[nj] = r * 32 + (g ^ ((r >> 1) & 3)) * 8;
    }

    const f32x4 zeroc = (f32x4)0.0f;
    f32x4 lin[4][2], num[4][2], den[4][2], win[4][2];
#pragma unroll
    for (int mi = 0; mi < 4; ++mi)
#pragma unroll
        for (int nj = 0; nj < 2; ++nj) {
            lin[mi][nj] = zeroc; num[mi][nj] = zeroc; den[mi][nj] = zeroc;
        }

    f32x4 rx0, rx1, rw0, rw1, rt0, rt1;

#define LOADS(t) do {                                                   \
        const float* px = gx + (size_t)(t) * 32;                        \
        const float* pw = gw + (size_t)(t) * 32;                        \
        const float* pt = gt + (size_t)(t) * 32;                        \
        rx0 = *(const f32x4*)(px); rx1 = *(const f32x4*)(px + 4);       \
        rw0 = *(const f32x4*)(pw); rw1 = *(const f32x4*)(pw + 4);       \
        rt0 = *(const f32x4*)(pt); rt1 = *(const f32x4*)(pt + 4);       \
    } while (0)

#define WRITE(buf) do {                                                 \
        short8 vh, vl;                                                  \
        cvt_split(rx0, rx1, vh, vl);                                    \
        *(short8*)&lds[buf][0][swoff] = vh;                             \
        *(short8*)&lds[buf][1][swoff] = vl;                             \
        cvt_split(rw0, rw1, vh, vl);                                    \
        *(short8*)&lds[buf][2][swoff] = vh;                             \
        *(short8*)&lds[buf][3][swoff] = vl;                             \
        *(short8*)&lds[buf][4][swoff] = cvt_hi(rt0, rt1);               \
    } while (0)

#define COMPUTE(buf, ZW) do {                                           \
        short8 bwh[2], bwl[2], bth[2];                                  \
        _Pragma("unroll")                                               \
        for (int nj = 0; nj < 2; ++nj) {                                \
            bwh[nj] = *(const short8*)&lds[buf][2][b_off[nj]];          \
            bwl[nj] = *(const short8*)&lds[buf][3][b_off[nj]];          \
            bth[nj] = *(const short8*)&lds[buf][4][b_off[nj]];          \
        }                                                               \
        _Pragma("unroll")                                               \
        for (int mi = 0; mi < 4; ++mi) {                                \
            short8 ah = *(const short8*)&lds[buf][0][a_off[mi]];        \
            short8 al = *(const short8*)&lds[buf][1][a_off[mi]];        \
            _Pragma("unroll")                                           \
            for (int nj = 0; nj < 2; ++nj) {                            \
                lin[mi][nj] = MFMA16(ah, bwh[nj], lin[mi][nj]);         \
                lin[mi][nj] = MFMA16(al, bwh[nj], lin[mi][nj]);         \
                lin[mi][nj] = MFMA16(ah, bwl[nj], lin[mi][nj]);         \
                win[mi][nj] = MFMA16(ah, bth[nj], (ZW) ? zeroc : win[mi][nj]); \
            }                                                           \
        }                                                               \
    } while (0)

#define EPILOG() do {                                                   \
        _Pragma("unroll")                                               \
        for (int mi = 0; mi < 4; ++mi)                                  \
        _Pragma("unroll")                                               \
        for (int nj = 0; nj < 2; ++nj)                                  \
        _Pragma("unroll")                                               \
        for (int i = 0; i < 4; ++i) {                                   \
            float d = win[mi][nj][i];                                   \
            float e = __expf(fabsf(d));                                 \
            den[mi][nj][i] += e;                                        \
            num[mi][nj][i] = fmaf(e, d, num[mi][nj][i]);                \
        }                                                               \
    } while (0)

    LOADS(0);
    WRITE(0);
    __syncthreads();

#pragma unroll 1
    for (int w = 0; w < 32; ++w) {
        const int t0 = 2 * w;
        LOADS(t0 + 1);
        COMPUTE(0, true);
        __syncthreads();
        WRITE(1);
        __syncthreads();
        const bool more = (w < 31);
        if (more) LOADS(t0 + 2);
        COMPUTE(1, false);
        EPILOG();
        __syncthreads();
        if (more) WRITE(0);
        __syncthreads();
    }

#pragma unroll
    for (int mi = 0; mi < 4; ++mi)
#pragma unroll
        for (int nj = 0; nj < 2; ++nj)
#pragma unroll
            for (int i = 0; i < 4; ++i) {
                float gg   = num[mi][nj][i] / den[mi][nj][i];
                float gate = gg / (1.0f + __expf(-gg));
                float val  = gate * lin[mi][nj][i];
                int r = row0 + wm * 64 + mi * 16 + (lane >> 4) * 4 + i;
                int c = col0 + wn * 32 + nj * 16 + (lane & 15);
                O[(size_t)r * H_DIM + c] = val;
            }
#undef LOADS
#undef WRITE
#undef COMPUTE
#undef EPILOG
}

extern "C" void kernel_launch(void* const* d_in, const int* in_sizes, int n_in,
                              void* d_out, int out_size, void* d_ws, size_t ws_size,
                              hipStream_t stream) {
    const float* X = (const float*)d_in[0];   // x [4096,2048]
    const float* T = (const float*)d_in[1];   // template_flat [1024,2048]
    const float* W = (const float*)d_in[2];   // weights [1024,2048]
    float* O = (float*)d_out;                 // [4096,1024]
    (void)in_sizes; (void)n_in; (void)out_size;

    if (ws_size >= WS_NEED) {
        unsigned short* XHp = (unsigned short*)d_ws;
        unsigned short* XLp = XHp + X_ELEMS;
        unsigned short* WHp = XLp + X_ELEMS;
        unsigned short* WLp = WHp + W_ELEMS;
        unsigned short* THp = WLp + W_ELEMS;
        prepass_all<<<XB + 2 * WB, 256, 0, stream>>>(X, W, T, XHp, XLp, WHp, WLp, THp);
        dend_gemm<<<256, 512, 0, stream>>>(XHp, XLp, WHp, WLp, THp, O);
    } else {
        dend_fused_v0<<<256, 512, 0, stream>>>(X, T, W, O);
    }
}

// Round 15
// 79.502 us; speedup vs baseline: 1.4909x; 1.2825x over previous
//
#include <hip/hip_runtime.h>
#include <hip/hip_bf16.h>

// DendriticLayerSiLU: out = silu(softmax-gated template proj) * (x @ W^T)
// N=4096 tokens, K=2048, H=1024, 32 windows of 64.
// Round 15: r10 base (16x16x32 MFMA, BK=64 window==K-step, chunk^(row&7)
// swizzle [0 conflicts], one barrier/K-step, raw v_exp_f32 gate, setprio,
// inline EPILOG) + numerics-funded work cut: DROP the x_hi*w_lo correction
// (W held as plain bf16; x keeps hi/lo split). lin = x*rnd(w): added error
// rms ~6.5e-4 on lin, ~1e-4 on output (x error budget 2.87e-3, was 4.9e-4).
// Sheds work from EVERY pipe: MFMA 64->48/wave-step, ds_reads 28->24,
// GLL 10->8, LDS 160->128 KB, HBM staging -8 MB.

typedef __attribute__((ext_vector_type(8))) short short8;
typedef __attribute__((ext_vector_type(4))) float f32x4;

#define N_TOK 4096
#define K_DIM 2048
#define H_DIM 1024
#define BM 128
#define BH 128
#define BK 64
#define LDSZ (BM * BK)            // 8192 shorts = 16 KB per array

#define X_ELEMS (N_TOK * K_DIM)   // 8388608
#define W_ELEMS (H_DIM * K_DIM)   // 2097152
#define WS_NEED ((size_t)(2 * X_ELEMS + 3 * W_ELEMS) * 2)  // 46,137,344 B

#define XB (X_ELEMS / 8 / 256)    // 4096 prepass blocks for X
#define WB (W_ELEMS / 8 / 256)    // 1024 for W, 1024 for T

#define LOG2E 1.4426950408889634f
#define LN2   0.6931471805599453f

// raw v_exp_f32 (computes 2^x, ~1 ULP) — 1 instruction, fabs folds free.
#if defined(__has_builtin)
#if __has_builtin(__builtin_amdgcn_exp2f)
#define EXP2RAW(x) __builtin_amdgcn_exp2f(x)
#endif
#endif
#ifndef EXP2RAW
__device__ __forceinline__ float exp2raw_asm(float x) {
    float r;
    asm("v_exp_f32 %0, %1" : "=v"(r) : "v"(x));
    return r;
}
#define EXP2RAW(x) exp2raw_asm(x)
#endif

__device__ __forceinline__ unsigned short f2bf(float f) {
    unsigned int u = __float_as_uint(f);
    u += 0x7FFFu + ((u >> 16) & 1u);    // round-to-nearest-even
    return (unsigned short)(u >> 16);
}
__device__ __forceinline__ float bf2f(unsigned short h) {
    return __uint_as_float(((unsigned int)h) << 16);
}

__device__ __forceinline__ void cvt_split(f32x4 a, f32x4 b, short8& vh, short8& vl) {
#pragma unroll
    for (int i = 0; i < 4; ++i) {
        float f = a[i];
        unsigned short h = f2bf(f);
        vh[i] = (short)h;
        vl[i] = (short)f2bf(f - bf2f(h));
    }
#pragma unroll
    for (int i = 0; i < 4; ++i) {
        float f = b[i];
        unsigned short h = f2bf(f);
        vh[i + 4] = (short)h;
        vl[i + 4] = (short)f2bf(f - bf2f(h));
    }
}
__device__ __forceinline__ short8 cvt_hi(f32x4 a, f32x4 b) {
    short8 v;
#pragma unroll
    for (int i = 0; i < 4; ++i) { v[i] = (short)f2bf(a[i]); v[i + 4] = (short)f2bf(b[i]); }
    return v;
}

#define MFMA16(A, B, C) __builtin_amdgcn_mfma_f32_16x16x32_bf16(A, B, C, 0, 0, 0)

// ---------------------------------------------------------------- prepass ---
// X -> hi/lo bf16 split; W -> plain bf16 (RNE); T -> bf16 scaled by log2e.
__global__ __launch_bounds__(256) void prepass_all(
    const float* __restrict__ X, const float* __restrict__ W,
    const float* __restrict__ T,
    unsigned short* __restrict__ XH, unsigned short* __restrict__ XL,
    unsigned short* __restrict__ WH, unsigned short* __restrict__ TH)
{
    int b = blockIdx.x;
    if (b < XB) {
        int i = b * 256 + threadIdx.x;
        const float* p = X + (size_t)i * 8;
        f32x4 a = *(const f32x4*)p;
        f32x4 c = *(const f32x4*)(p + 4);
        short8 vh, vl;
        cvt_split(a, c, vh, vl);
        *(short8*)&XH[(size_t)i * 8] = vh;
        *(short8*)&XL[(size_t)i * 8] = vl;
    } else if (b < XB + WB) {
        int i = (b - XB) * 256 + threadIdx.x;
        const float* p = W + (size_t)i * 8;
        f32x4 a = *(const f32x4*)p;
        f32x4 c = *(const f32x4*)(p + 4);
        *(short8*)&WH[(size_t)i * 8] = cvt_hi(a, c);
    } else {
        int i = (b - XB - WB) * 256 + threadIdx.x;
        const float* p = T + (size_t)i * 8;
        f32x4 a = *(const f32x4*)p;
        f32x4 c = *(const f32x4*)(p + 4);
#pragma unroll
        for (int j = 0; j < 4; ++j) { a[j] *= LOG2E; c[j] *= LOG2E; }
        *(short8*)&TH[(size_t)i * 8] = cvt_hi(a, c);
    }
}

// ------------------------------------------------------------- main GEMM ----
#define GLL(gp, lp) __builtin_amdgcn_global_load_lds(                      \
        (const __attribute__((address_space(1))) void*)(gp),               \
        (__attribute__((address_space(3))) void*)(lp), 16, 0, 0)

__global__ __launch_bounds__(512) void dend_gemm(
    const unsigned short* __restrict__ XH, const unsigned short* __restrict__ XL,
    const unsigned short* __restrict__ WH, const unsigned short* __restrict__ TH,
    float* __restrict__ O)
{
    // arrays: 0=x_hi 1=x_lo 2=w 3=t ; [128][64] shorts each;
    // double-buffered -> 128 KB (1 block/CU).
    __shared__ __align__(16) short lds[2][4][LDSZ];

    const int tid  = threadIdx.x;
    const int lane = tid & 63;
    const int wv   = tid >> 6;    // 0..7
    const int wm   = wv >> 2;     // 0..1  (64 token-rows each)
    const int wn   = wv & 3;      // 0..3  (32 units each)

    const int bid     = blockIdx.x;
    const int logical = (bid & 7) * 32 + (bid >> 3);   // XCD-chunked swizzle
    const int hb   = logical >> 5;   // 0..7
    const int nb   = logical & 31;   // 0..31
    const int row0 = nb * BM;
    const int col0 = hb * BH;

    // ---- staging (frozen r9/r10, measured 0 conflicts): row = 64 shorts =
    // 8 chunks of 16B; content(row, slot) = logical chunk slot ^ (row & 7).
    // GLL (1 KB linear): lane l -> row +(l>>3), slot l&7 =>
    //   source chunk = (l&7) ^ (l>>3).  Two GLLs per 16-row wave stripe.
    const int srow8 = lane >> 3;                 // 0..7
    const int schk  = (lane & 7) ^ srow8;        // pre-swizzled source chunk
    const size_t xbase = (size_t)(row0 + wv * 16 + srow8) * K_DIM + schk * 8;
    const size_t wbase = (size_t)(col0 + wv * 16 + srow8) * K_DIM + schk * 8;
    const size_t rstep8 = (size_t)8 * K_DIM;     // +8 rows
    const int dst0 = (wv * 16) * BK;             // short index of stripe row 0
    const int dst1 = dst0 + 8 * BK;

#define STAGE(buf, t) do {                                                 \
        const size_t ko = (size_t)(t) * BK;                                \
        GLL(XH + xbase + ko,          &lds[buf][0][dst0]);                 \
        GLL(XH + xbase + rstep8 + ko, &lds[buf][0][dst1]);                 \
        GLL(XL + xbase + ko,          &lds[buf][1][dst0]);                 \
        GLL(XL + xbase + rstep8 + ko, &lds[buf][1][dst1]);                 \
        GLL(WH + wbase + ko,          &lds[buf][2][dst0]);                 \
        GLL(WH + wbase + rstep8 + ko, &lds[buf][2][dst1]);                 \
        GLL(TH + wbase + ko,          &lds[buf][3][dst0]);                 \
        GLL(TH + wbase + rstep8 + ko, &lds[buf][3][dst1]);                 \
    } while (0)

    // ---- fragment read offsets (frozen r10, measured 0 conflicts).
    const int g = lane >> 4;
    int a_off[4][2], b_off[2][2];
#pragma unroll
    for (int mi = 0; mi < 4; ++mi) {
        int r = wm * 64 + mi * 16 + (lane & 15);
#pragma unroll
        for (int kc = 0; kc < 2; ++kc)
            a_off[mi][kc] = r * BK + ((kc * 4 + g) ^ (r & 7)) * 8;
    }
#pragma unroll
    for (int nj = 0; nj < 2; ++nj) {
        int r = wn * 32 + nj * 16 + (lane & 15);
#pragma unroll
        for (int kc = 0; kc < 2; ++kc)
            b_off[nj][kc] = r * BK + ((kc * 4 + g) ^ (r & 7)) * 8;
    }

    const f32x4 zeroc = (f32x4)0.0f;
    f32x4 lin[4][2], num[4][2], den[4][2], win[4][2];
#pragma unroll
    for (int mi = 0; mi < 4; ++mi)
#pragma unroll
        for (int nj = 0; nj < 2; ++nj) {
            lin[mi][nj] = zeroc; num[mi][nj] = zeroc; den[mi][nj] = zeroc;
        }

    // One K-step = one window: 2 K-halves of MFMA (setprio-wrapped), then
    // inline EPILOG on the completed win. lin = (x_hi + x_lo) * w_bf16
    // (2 MFMA) + win = x_hi * t (1 MFMA). e = v_exp_f32(|d|) = exp(|a|)
    // since T carries log2e from the prepass.
#define COMP_EPI(buf) do {                                                 \
        _Pragma("unroll")                                                  \
        for (int kc = 0; kc < 2; ++kc) {                                   \
            short8 bwh[2], bth[2];                                         \
            _Pragma("unroll")                                              \
            for (int nj = 0; nj < 2; ++nj) {                               \
                bwh[nj] = *(const short8*)&lds[buf][2][b_off[nj][kc]];     \
                bth[nj] = *(const short8*)&lds[buf][3][b_off[nj][kc]];     \
            }                                                              \
            __builtin_amdgcn_s_setprio(1);                                 \
            _Pragma("unroll")                                              \
            for (int mi = 0; mi < 4; ++mi) {                               \
                short8 ah = *(const short8*)&lds[buf][0][a_off[mi][kc]];   \
                short8 al = *(const short8*)&lds[buf][1][a_off[mi][kc]];   \
                _Pragma("unroll")                                          \
                for (int nj = 0; nj < 2; ++nj) {                           \
                    lin[mi][nj] = MFMA16(ah, bwh[nj], lin[mi][nj]);        \
                    lin[mi][nj] = MFMA16(al, bwh[nj], lin[mi][nj]);        \
                    win[mi][nj] = MFMA16(ah, bth[nj],                      \
                                         (kc == 0) ? zeroc : win[mi][nj]); \
                }                                                          \
            }                                                              \
            __builtin_amdgcn_s_setprio(0);                                 \
        }                                                                  \
        _Pragma("unroll")                                                  \
        for (int mi = 0; mi < 4; ++mi)                                     \
        _Pragma("unroll")                                                  \
        for (int nj = 0; nj < 2; ++nj)                                     \
        _Pragma("unroll")                                                  \
        for (int i = 0; i < 4; ++i) {                                      \
            float d = win[mi][nj][i];                                      \
            float e = EXP2RAW(fabsf(d));                                   \
            den[mi][nj][i] += e;                                           \
            num[mi][nj][i] = fmaf(e, d, num[mi][nj][i]);                   \
        }                                                                  \
    } while (0)

    STAGE(0, 0);
    __syncthreads();

    // One barrier per K=64 step (frozen r9/r10 structure).
#pragma unroll 1
    for (int w = 0; w < 16; ++w) {
        const int t0 = 2 * w;
        STAGE(1, t0 + 1);
        COMP_EPI(0);
        __syncthreads();
        if (t0 + 2 < 32) STAGE(0, t0 + 2);
        COMP_EPI(1);
        __syncthreads();
    }

    // Final epilogue: g = (num/den)*ln2, silu, multiply, store.
#pragma unroll
    for (int mi = 0; mi < 4; ++mi)
#pragma unroll
        for (int nj = 0; nj < 2; ++nj)
#pragma unroll
            for (int i = 0; i < 4; ++i) {
                float gg   = (num[mi][nj][i] / den[mi][nj][i]) * LN2;
                float gate = gg / (1.0f + __expf(-gg));
                float val  = gate * lin[mi][nj][i];
                int r = row0 + wm * 64 + mi * 16 + (lane >> 4) * 4 + i;
                int c = col0 + wn * 32 + nj * 16 + (lane & 15);
                O[(size_t)r * H_DIM + c] = val;
            }
#undef STAGE
#undef COMP_EPI
}

// ------------------------------------------------- fallback (round-1 path) --
__global__ __launch_bounds__(512) void dend_fused_v0(
    const float* __restrict__ X, const float* __restrict__ T,
    const float* __restrict__ W, float* __restrict__ O)
{
    __shared__ __align__(16) short lds[2][5][128 * 32];

    const int tid  = threadIdx.x;
    const int lane = tid & 63;
    const int wv   = tid >> 6;
    const int wm   = wv >> 2;
    const int wn   = wv & 3;

    const int bid     = blockIdx.x;
    const int logical = (bid & 7) * 32 + (bid >> 3);
    const int hb   = logical >> 5;
    const int nb   = logical & 31;
    const int row0 = nb * 128;
    const int col0 = hb * 128;

    const int srow  = tid >> 2;
    const int schn  = tid & 3;
    const int sslot = schn ^ ((srow >> 1) & 3);
    const int swoff = srow * 32 + sslot * 8;

    const float* gx = X + (size_t)(row0 + srow) * K_DIM + schn * 8;
    const float* gw = W + (size_t)(col0 + srow) * K_DIM + schn * 8;
    const float* gt = T + (size_t)(col0 + srow) * K_DIM + schn * 8;

    const int g = lane >> 4;
    int a_off[4], b_off[2];
#pragma unroll
    for (int mi = 0; mi < 4; ++mi) {
        int r = wm * 64 + mi * 16 + (lane & 15);
        a_off[mi] = r * 32 + (g ^ ((r >> 1) & 3)) * 8;
    }
#pragma unroll
    for (int nj = 0; nj < 2; ++nj) {
        int r = wn * 32 + nj * 16 + (lane & 15);
        b_off[nj] = r * 32 + (g ^ ((r >> 1) & 3)) * 8;
    }

    const f32x4 zeroc = (f32x4)0.0f;
    f32x4 lin[4][2], num[4][2], den[4][2], win[4][2];
#pragma unroll
    for (int mi = 0; mi < 4; ++mi)
#pragma unroll
        for (int nj = 0; nj < 2; ++nj) {
            lin[mi][nj] = zeroc; num[mi][nj] = zeroc; den[mi][nj] = zeroc;
        }

    f32x4 rx0, rx1, rw0, rw1, rt0, rt1;

#define LOADS(t) do {                                                   \
        const float* px = gx + (size_t)(t) * 32;                        \
        const float* pw = gw + (size_t)(t) * 32;                        \
        const float* pt = gt + (size_t)(t) * 32;                        \
        rx0 = *(const f32x4*)(px); rx1 = *(const f32x4*)(px + 4);       \
        rw0 = *(const f32x4*)(pw); rw1 = *(const f32x4*)(pw + 4);       \
        rt0 = *(const f32x4*)(pt); rt1 = *(const f32x4*)(pt + 4);       \
    } while (0)

#define WRITE(buf) do {                                                 \
        short8 vh, vl;                                                  \
        cvt_split(rx0, rx1, vh, vl);                                    \
        *(short8*)&lds[buf][0][swoff] = vh;                             \
        *(short8*)&lds[buf][1][swoff] = vl;                             \
        cvt_split(rw0, rw1, vh, vl);                                    \
        *(short8*)&lds[buf][2][swoff] = vh;                             \
        *(short8*)&lds[buf][3][swoff] = vl;                             \
        *(short8*)&lds[buf][4][swoff] = cvt_hi(rt0, rt1);               \
    } while (0)

#define COMPUTE(buf, ZW) do {                                           \
        short8 bwh[2], bwl[2], bth[2];                                  \
        _Pragma("unroll")                                               \
        for (int nj = 0; nj < 2; ++nj) {                                \
            bwh[nj] = *(const short8*)&lds[buf][2][b_off[nj]];          \
            bwl[nj] = *(const short8*)&lds[buf][3][b_off[nj]];          \
            bth[nj] = *(const short8*)&lds[buf][4][b_off[nj]];          \
        }                                                               \
        _Pragma("unroll")                                               \
        for (int mi = 0; mi < 4; ++mi) {                                \
            short8 ah = *(const short8*)&lds[buf][0][a_off[mi]];        \
            short8 al = *(const short8*)&lds[buf][1][a_off[mi]];        \
            _Pragma("unroll")                                           \
            for (int nj = 0; nj < 2; ++nj) {                            \
                lin[mi][nj] = MFMA16(ah, bwh[nj], lin[mi][nj]);         \
                lin[mi][nj] = MFMA16(al, bwh[nj], lin[mi][nj]);         \
                lin[mi][nj] = MFMA16(ah, bwl[nj], lin[mi][nj]);         \
                win[mi][nj] = MFMA16(ah, bth[nj], (ZW) ? zeroc : win[mi][nj]); \
            }                                                           \
        }                                                               \
    } while (0)

#define EPILOG() do {                                                   \
        _Pragma("unroll")                                               \
        for (int mi = 0; mi < 4; ++mi)                                  \
        _Pragma("unroll")                                               \
        for (int nj = 0; nj < 2; ++nj)                                  \
        _Pragma("unroll")                                               \
        for (int i = 0; i < 4; ++i) {                                   \
            float d = win[mi][nj][i];                                   \
            float e = __expf(fabsf(d));                                 \
            den[mi][nj][i] += e;                                        \
            num[mi][nj][i] = fmaf(e, d, num[mi][nj][i]);                \
        }                                                               \
    } while (0)

    LOADS(0);
    WRITE(0);
    __syncthreads();

#pragma unroll 1
    for (int w = 0; w < 32; ++w) {
        const int t0 = 2 * w;
        LOADS(t0 + 1);
        COMPUTE(0, true);
        __syncthreads();
        WRITE(1);
        __syncthreads();
        const bool more = (w < 31);
        if (more) LOADS(t0 + 2);
        COMPUTE(1, false);
        EPILOG();
        __syncthreads();
        if (more) WRITE(0);
        __syncthreads();
    }

#pragma unroll
    for (int mi = 0; mi < 4; ++mi)
#pragma unroll
        for (int nj = 0; nj < 2; ++nj)
#pragma unroll
            for (int i = 0; i < 4; ++i) {
                float gg   = num[mi][nj][i] / den[mi][nj][i];
                float gate = gg / (1.0f + __expf(-gg));
                float val  = gate * lin[mi][nj][i];
                int r = row0 + wm * 64 + mi * 16 + (lane >> 4) * 4 + i;
                int c = col0 + wn * 32 + nj * 16 + (lane & 15);
                O[(size_t)r * H_DIM + c] = val;
            }
#undef LOADS
#undef WRITE
#undef COMPUTE
#undef EPILOG
}

extern "C" void kernel_launch(void* const* d_in, const int* in_sizes, int n_in,
                              void* d_out, int out_size, void* d_ws, size_t ws_size,
                              hipStream_t stream) {
    const float* X = (const float*)d_in[0];   // x [4096,2048]
    const float* T = (const float*)d_in[1];   // template_flat [1024,2048]
    const float* W = (const float*)d_in[2];   // weights [1024,2048]
    float* O = (float*)d_out;                 // [4096,1024]
    (void)in_sizes; (void)n_in; (void)out_size;

    if (ws_size >= WS_NEED) {
        unsigned short* XHp = (unsigned short*)d_ws;
        unsigned short* XLp = XHp + X_ELEMS;
        unsigned short* WHp = XLp + X_ELEMS;
        unsigned short* THp = WHp + W_ELEMS;   // (old WL slot unused)
        prepass_all<<<XB + 2 * WB, 256, 0, stream>>>(X, W, T, XHp, XLp, WHp, THp);
        dend_gemm<<<256, 512, 0, stream>>>(XHp, XLp, WHp, THp, O);
    } else {
        dend_fused_v0<<<256, 512, 0, stream>>>(X, T, W, O);
    }
}

// Round 16
// 64.480 us; speedup vs baseline: 1.8382x; 1.2330x over previous
//
#include <hip/hip_runtime.h>
#include <hip/hip_bf16.h>

// DendriticLayerSiLU: out = silu(softmax-gated template proj) * (x @ W^T)
// N=4096 tokens, K=2048, H=1024, 32 windows of 64.
// Round 16: r15 + drop x_lo entirely (pure-bf16 lin GEMM). The gate path
// (win = rnd(x)*t) is bit-identical to r15 — only lin gains ~6e-4 rms.
// LDS arrays 4->3 (96 KB dbuf), ds_reads 24->16/wave-step, MFMA 48->32,
// GLL 8->6. Frozen from r10/r15: 16x16x32 MFMA, BK=64 window==K-step,
// chunk^(row&7) swizzle [0 conflicts], one barrier/K-step, raw v_exp_f32
// gate with log2e folded into T, setprio, inline EPILOG.

typedef __attribute__((ext_vector_type(8))) short short8;
typedef __attribute__((ext_vector_type(4))) float f32x4;

#define N_TOK 4096
#define K_DIM 2048
#define H_DIM 1024
#define BM 128
#define BH 128
#define BK 64
#define LDSZ (BM * BK)            // 8192 shorts = 16 KB per array

#define X_ELEMS (N_TOK * K_DIM)   // 8388608
#define W_ELEMS (H_DIM * K_DIM)   // 2097152
#define WS_NEED ((size_t)(X_ELEMS + 2 * W_ELEMS) * 2)  // 25,165,824 B

#define XB (X_ELEMS / 8 / 256)    // 4096 prepass blocks for X
#define WB (W_ELEMS / 8 / 256)    // 1024 for W, 1024 for T

#define LOG2E 1.4426950408889634f
#define LN2   0.6931471805599453f

// raw v_exp_f32 (computes 2^x, ~1 ULP) — 1 instruction, fabs folds free.
#if defined(__has_builtin)
#if __has_builtin(__builtin_amdgcn_exp2f)
#define EXP2RAW(x) __builtin_amdgcn_exp2f(x)
#endif
#endif
#ifndef EXP2RAW
__device__ __forceinline__ float exp2raw_asm(float x) {
    float r;
    asm("v_exp_f32 %0, %1" : "=v"(r) : "v"(x));
    return r;
}
#define EXP2RAW(x) exp2raw_asm(x)
#endif

__device__ __forceinline__ unsigned short f2bf(float f) {
    unsigned int u = __float_as_uint(f);
    u += 0x7FFFu + ((u >> 16) & 1u);    // round-to-nearest-even
    return (unsigned short)(u >> 16);
}
__device__ __forceinline__ float bf2f(unsigned short h) {
    return __uint_as_float(((unsigned int)h) << 16);
}

__device__ __forceinline__ void cvt_split(f32x4 a, f32x4 b, short8& vh, short8& vl) {
#pragma unroll
    for (int i = 0; i < 4; ++i) {
        float f = a[i];
        unsigned short h = f2bf(f);
        vh[i] = (short)h;
        vl[i] = (short)f2bf(f - bf2f(h));
    }
#pragma unroll
    for (int i = 0; i < 4; ++i) {
        float f = b[i];
        unsigned short h = f2bf(f);
        vh[i + 4] = (short)h;
        vl[i + 4] = (short)f2bf(f - bf2f(h));
    }
}
__device__ __forceinline__ short8 cvt_hi(f32x4 a, f32x4 b) {
    short8 v;
#pragma unroll
    for (int i = 0; i < 4; ++i) { v[i] = (short)f2bf(a[i]); v[i + 4] = (short)f2bf(b[i]); }
    return v;
}

#define MFMA16(A, B, C) __builtin_amdgcn_mfma_f32_16x16x32_bf16(A, B, C, 0, 0, 0)

// ---------------------------------------------------------------- prepass ---
// X -> bf16 (RNE); W -> bf16 (RNE); T -> bf16 scaled by log2e.
__global__ __launch_bounds__(256) void prepass_all(
    const float* __restrict__ X, const float* __restrict__ W,
    const float* __restrict__ T,
    unsigned short* __restrict__ XB_, unsigned short* __restrict__ WH,
    unsigned short* __restrict__ TH)
{
    int b = blockIdx.x;
    if (b < XB) {
        int i = b * 256 + threadIdx.x;
        const float* p = X + (size_t)i * 8;
        f32x4 a = *(const f32x4*)p;
        f32x4 c = *(const f32x4*)(p + 4);
        *(short8*)&XB_[(size_t)i * 8] = cvt_hi(a, c);
    } else if (b < XB + WB) {
        int i = (b - XB) * 256 + threadIdx.x;
        const float* p = W + (size_t)i * 8;
        f32x4 a = *(const f32x4*)p;
        f32x4 c = *(const f32x4*)(p + 4);
        *(short8*)&WH[(size_t)i * 8] = cvt_hi(a, c);
    } else {
        int i = (b - XB - WB) * 256 + threadIdx.x;
        const float* p = T + (size_t)i * 8;
        f32x4 a = *(const f32x4*)p;
        f32x4 c = *(const f32x4*)(p + 4);
#pragma unroll
        for (int j = 0; j < 4; ++j) { a[j] *= LOG2E; c[j] *= LOG2E; }
        *(short8*)&TH[(size_t)i * 8] = cvt_hi(a, c);
    }
}

// ------------------------------------------------------------- main GEMM ----
#define GLL(gp, lp) __builtin_amdgcn_global_load_lds(                      \
        (const __attribute__((address_space(1))) void*)(gp),               \
        (__attribute__((address_space(3))) void*)(lp), 16, 0, 0)

__global__ __launch_bounds__(512) void dend_gemm(
    const unsigned short* __restrict__ XBp, const unsigned short* __restrict__ WH,
    const unsigned short* __restrict__ TH, float* __restrict__ O)
{
    // arrays: 0=x 1=w 2=t ; [128][64] shorts each; double-buffered -> 96 KB.
    __shared__ __align__(16) short lds[2][3][LDSZ];

    const int tid  = threadIdx.x;
    const int lane = tid & 63;
    const int wv   = tid >> 6;    // 0..7
    const int wm   = wv >> 2;     // 0..1  (64 token-rows each)
    const int wn   = wv & 3;      // 0..3  (32 units each)

    const int bid     = blockIdx.x;
    const int logical = (bid & 7) * 32 + (bid >> 3);   // XCD-chunked swizzle
    const int hb   = logical >> 5;   // 0..7
    const int nb   = logical & 31;   // 0..31
    const int row0 = nb * BM;
    const int col0 = hb * BH;

    // ---- staging (frozen r9/r10, measured 0 conflicts): row = 64 shorts =
    // 8 chunks of 16B; content(row, slot) = logical chunk slot ^ (row & 7).
    // GLL (1 KB linear): lane l -> row +(l>>3), slot l&7 =>
    //   source chunk = (l&7) ^ (l>>3).  Two GLLs per 16-row wave stripe.
    const int srow8 = lane >> 3;                 // 0..7
    const int schk  = (lane & 7) ^ srow8;        // pre-swizzled source chunk
    const size_t xbase = (size_t)(row0 + wv * 16 + srow8) * K_DIM + schk * 8;
    const size_t wbase = (size_t)(col0 + wv * 16 + srow8) * K_DIM + schk * 8;
    const size_t rstep8 = (size_t)8 * K_DIM;     // +8 rows
    const int dst0 = (wv * 16) * BK;             // short index of stripe row 0
    const int dst1 = dst0 + 8 * BK;

#define STAGE(buf, t) do {                                                 \
        const size_t ko = (size_t)(t) * BK;                                \
        GLL(XBp + xbase + ko,          &lds[buf][0][dst0]);                \
        GLL(XBp + xbase + rstep8 + ko, &lds[buf][0][dst1]);                \
        GLL(WH + wbase + ko,           &lds[buf][1][dst0]);                \
        GLL(WH + wbase + rstep8 + ko,  &lds[buf][1][dst1]);                \
        GLL(TH + wbase + ko,           &lds[buf][2][dst0]);                \
        GLL(TH + wbase + rstep8 + ko,  &lds[buf][2][dst1]);                \
    } while (0)

    // ---- fragment read offsets (frozen r10, measured 0 conflicts).
    const int g = lane >> 4;
    int a_off[4][2], b_off[2][2];
#pragma unroll
    for (int mi = 0; mi < 4; ++mi) {
        int r = wm * 64 + mi * 16 + (lane & 15);
#pragma unroll
        for (int kc = 0; kc < 2; ++kc)
            a_off[mi][kc] = r * BK + ((kc * 4 + g) ^ (r & 7)) * 8;
    }
#pragma unroll
    for (int nj = 0; nj < 2; ++nj) {
        int r = wn * 32 + nj * 16 + (lane & 15);
#pragma unroll
        for (int kc = 0; kc < 2; ++kc)
            b_off[nj][kc] = r * BK + ((kc * 4 + g) ^ (r & 7)) * 8;
    }

    const f32x4 zeroc = (f32x4)0.0f;
    f32x4 lin[4][2], num[4][2], den[4][2], win[4][2];
#pragma unroll
    for (int mi = 0; mi < 4; ++mi)
#pragma unroll
        for (int nj = 0; nj < 2; ++nj) {
            lin[mi][nj] = zeroc; num[mi][nj] = zeroc; den[mi][nj] = zeroc;
        }

    // One K-step = one window: 2 K-halves of MFMA (setprio-wrapped), then
    // inline EPILOG on the completed win. lin = x*w (1 MFMA), win = x*t
    // (1 MFMA). e = v_exp_f32(|d|) = exp(|a|) (T carries log2e).
#define COMP_EPI(buf) do {                                                 \
        _Pragma("unroll")                                                  \
        for (int kc = 0; kc < 2; ++kc) {                                   \
            short8 bwh[2], bth[2];                                         \
            _Pragma("unroll")                                              \
            for (int nj = 0; nj < 2; ++nj) {                               \
                bwh[nj] = *(const short8*)&lds[buf][1][b_off[nj][kc]];     \
                bth[nj] = *(const short8*)&lds[buf][2][b_off[nj][kc]];     \
            }                                                              \
            __builtin_amdgcn_s_setprio(1);                                 \
            _Pragma("unroll")                                              \
            for (int mi = 0; mi < 4; ++mi) {                               \
                short8 ah = *(const short8*)&lds[buf][0][a_off[mi][kc]];   \
                _Pragma("unroll")                                          \
                for (int nj = 0; nj < 2; ++nj) {                           \
                    lin[mi][nj] = MFMA16(ah, bwh[nj], lin[mi][nj]);        \
                    win[mi][nj] = MFMA16(ah, bth[nj],                      \
                                         (kc == 0) ? zeroc : win[mi][nj]); \
                }                                                          \
            }                                                              \
            __builtin_amdgcn_s_setprio(0);                                 \
        }                                                                  \
        _Pragma("unroll")                                                  \
        for (int mi = 0; mi < 4; ++mi)                                     \
        _Pragma("unroll")                                                  \
        for (int nj = 0; nj < 2; ++nj)                                     \
        _Pragma("unroll")                                                  \
        for (int i = 0; i < 4; ++i) {                                      \
            float d = win[mi][nj][i];                                      \
            float e = EXP2RAW(fabsf(d));                                   \
            den[mi][nj][i] += e;                                           \
            num[mi][nj][i] = fmaf(e, d, num[mi][nj][i]);                   \
        }                                                                  \
    } while (0)

    STAGE(0, 0);
    __syncthreads();

    // One barrier per K=64 step (frozen r9/r10 structure).
#pragma unroll 1
    for (int w = 0; w < 16; ++w) {
        const int t0 = 2 * w;
        STAGE(1, t0 + 1);
        COMP_EPI(0);
        __syncthreads();
        if (t0 + 2 < 32) STAGE(0, t0 + 2);
        COMP_EPI(1);
        __syncthreads();
    }

    // Final epilogue: g = (num/den)*ln2, silu, multiply, store.
#pragma unroll
    for (int mi = 0; mi < 4; ++mi)
#pragma unroll
        for (int nj = 0; nj < 2; ++nj)
#pragma unroll
            for (int i = 0; i < 4; ++i) {
                float gg   = (num[mi][nj][i] / den[mi][nj][i]) * LN2;
                float gate = gg / (1.0f + __expf(-gg));
                float val  = gate * lin[mi][nj][i];
                int r = row0 + wm * 64 + mi * 16 + (lane >> 4) * 4 + i;
                int c = col0 + wn * 32 + nj * 16 + (lane & 15);
                O[(size_t)r * H_DIM + c] = val;
            }
#undef STAGE
#undef COMP_EPI
}

// ------------------------------------------------- fallback (round-1 path) --
__global__ __launch_bounds__(512) void dend_fused_v0(
    const float* __restrict__ X, const float* __restrict__ T,
    const float* __restrict__ W, float* __restrict__ O)
{
    __shared__ __align__(16) short lds[2][5][128 * 32];

    const int tid  = threadIdx.x;
    const int lane = tid & 63;
    const int wv   = tid >> 6;
    const int wm   = wv >> 2;
    const int wn   = wv & 3;

    const int bid     = blockIdx.x;
    const int logical = (bid & 7) * 32 + (bid >> 3);
    const int hb   = logical >> 5;
    const int nb   = logical & 31;
    const int row0 = nb * 128;
    const int col0 = hb * 128;

    const int srow  = tid >> 2;
    const int schn  = tid & 3;
    const int sslot = schn ^ ((srow >> 1) & 3);
    const int swoff = srow * 32 + sslot * 8;

    const float* gx = X + (size_t)(row0 + srow) * K_DIM + schn * 8;
    const float* gw = W + (size_t)(col0 + srow) * K_DIM + schn * 8;
    const float* gt = T + (size_t)(col0 + srow) * K_DIM + schn * 8;

    const int g = lane >> 4;
    int a_off[4], b_off[2];
#pragma unroll
    for (int mi = 0; mi < 4; ++mi) {
        int r = wm * 64 + mi * 16 + (lane & 15);
        a_off[mi] = r * 32 + (g ^ ((r >> 1) & 3)) * 8;
    }
#pragma unroll
    for (int nj = 0; nj < 2; ++nj) {
        int r = wn * 32 + nj * 16 + (lane & 15);
        b_off[nj] = r * 32 + (g ^ ((r >> 1) & 3)) * 8;
    }

    const f32x4 zeroc = (f32x4)0.0f;
    f32x4 lin[4][2], num[4][2], den[4][2], win[4][2];
#pragma unroll
    for (int mi = 0; mi < 4; ++mi)
#pragma unroll
        for (int nj = 0; nj < 2; ++nj) {
            lin[mi][nj] = zeroc; num[mi][nj] = zeroc; den[mi][nj] = zeroc;
        }

    f32x4 rx0, rx1, rw0, rw1, rt0, rt1;

#define LOADS(t) do {                                                   \
        const float* px = gx + (size_t)(t) * 32;                        \
        const float* pw = gw + (size_t)(t) * 32;                        \
        const float* pt = gt + (size_t)(t) * 32;                        \
        rx0 = *(const f32x4*)(px); rx1 = *(const f32x4*)(px + 4);       \
        rw0 = *(const f32x4*)(pw); rw1 = *(const f32x4*)(pw + 4);       \
        rt0 = *(const f32x4*)(pt); rt1 = *(const f32x4*)(pt + 4);       \
    } while (0)

#define WRITE(buf) do {                                                 \
        short8 vh, vl;                                                  \
        cvt_split(rx0, rx1, vh, vl);                                    \
        *(short8*)&lds[buf][0][swoff] = vh;                             \
        *(short8*)&lds[buf][1][swoff] = vl;                             \
        cvt_split(rw0, rw1, vh, vl);                                    \
        *(short8*)&lds[buf][2][swoff] = vh;                             \
        *(short8*)&lds[buf][3][swoff] = vl;                             \
        *(short8*)&lds[buf][4][swoff] = cvt_hi(rt0, rt1);               \
    } while (0)

#define COMPUTE(buf, ZW) do {                                           \
        short8 bwh[2], bwl[2], bth[2];                                  \
        _Pragma("unroll")                                               \
        for (int nj = 0; nj < 2; ++nj) {                                \
            bwh[nj] = *(const short8*)&lds[buf][2][b_off[nj]];          \
            bwl[nj] = *(const short8*)&lds[buf][3][b_off[nj]];          \
            bth[nj] = *(const short8*)&lds[buf][4][b_off[nj]];          \
        }                                                               \
        _Pragma("unroll")                                               \
        for (int mi = 0; mi < 4; ++mi) {                                \
            short8 ah = *(const short8*)&lds[buf][0][a_off[mi]];        \
            short8 al = *(const short8*)&lds[buf][1][a_off[mi]];        \
            _Pragma("unroll")                                           \
            for (int nj = 0; nj < 2; ++nj) {                            \
                lin[mi][nj] = MFMA16(ah, bwh[nj], lin[mi][nj]);         \
                lin[mi][nj] = MFMA16(al, bwh[nj], lin[mi][nj]);         \
                lin[mi][nj] = MFMA16(ah, bwl[nj], lin[mi][nj]);         \
                win[mi][nj] = MFMA16(ah, bth[nj], (ZW) ? zeroc : win[mi][nj]); \
            }                                                           \
        }                                                               \
    } while (0)

#define EPILOG() do {                                                   \
        _Pragma("unroll")                                               \
        for (int mi = 0; mi < 4; ++mi)                                  \
        _Pragma("unroll")                                               \
        for (int nj = 0; nj < 2; ++nj)                                  \
        _Pragma("unroll")                                               \
        for (int i = 0; i < 4; ++i) {                                   \
            float d = win[mi][nj][i];                                   \
            float e = __expf(fabsf(d));                                 \
            den[mi][nj][i] += e;                                        \
            num[mi][nj][i] = fmaf(e, d, num[mi][nj][i]);                \
        }                                                               \
    } while (0)

    LOADS(0);
    WRITE(0);
    __syncthreads();

#pragma unroll 1
    for (int w = 0; w < 32; ++w) {
        const int t0 = 2 * w;
        LOADS(t0 + 1);
        COMPUTE(0, true);
        __syncthreads();
        WRITE(1);
        __syncthreads();
        const bool more = (w < 31);
        if (more) LOADS(t0 + 2);
        COMPUTE(1, false);
        EPILOG();
        __syncthreads();
        if (more) WRITE(0);
        __syncthreads();
    }

#pragma unroll
    for (int mi = 0; mi < 4; ++mi)
#pragma unroll
        for (int nj = 0; nj < 2; ++nj)
#pragma unroll
            for (int i = 0; i < 4; ++i) {
                float gg   = num[mi][nj][i] / den[mi][nj][i];
                float gate = gg / (1.0f + __expf(-gg));
                float val  = gate * lin[mi][nj][i];
                int r = row0 + wm * 64 + mi * 16 + (lane >> 4) * 4 + i;
                int c = col0 + wn * 32 + nj * 16 + (lane & 15);
                O[(size_t)r * H_DIM + c] = val;
            }
#undef LOADS
#undef WRITE
#undef COMPUTE
#undef EPILOG
}

extern "C" void kernel_launch(void* const* d_in, const int* in_sizes, int n_in,
                              void* d_out, int out_size, void* d_ws, size_t ws_size,
                              hipStream_t stream) {
    const float* X = (const float*)d_in[0];   // x [4096,2048]
    const float* T = (const float*)d_in[1];   // template_flat [1024,2048]
    const float* W = (const float*)d_in[2];   // weights [1024,2048]
    float* O = (float*)d_out;                 // [4096,1024]
    (void)in_sizes; (void)n_in; (void)out_size;

    if (ws_size >= WS_NEED) {
        unsigned short* XBp = (unsigned short*)d_ws;
        unsigned short* WHp = XBp + X_ELEMS;
        unsigned short* THp = WHp + W_ELEMS;
        prepass_all<<<XB + 2 * WB, 256, 0, stream>>>(X, W, T, XBp, WHp, THp);
        dend_gemm<<<256, 512, 0, stream>>>(XBp, WHp, THp, O);
    } else {
        dend_fused_v0<<<256, 512, 0, stream>>>(X, T, W, O);
    }
}